// Round 8
// baseline (239.606 us; speedup 1.0000x reference)
//
#include <hip/hip_runtime.h>

#define NB 32
#define NC 511      // T-1 context positions
#define NK 8        // senses (center)
#define NS 8        // senses (context)
#define ND 300      // embedding dim
#define ND4 75      // float4 per row
#define NCG 16      // c-groups per b (32 c's per block) -- 512 blocks total
#define GPB 8       // sub-groups of 4 c's per block
#define EPS_COS 1e-8f

// Math notes (verified R1-R6, absmax 0.0):
//  - positional log-weight is constant => center_pos/query_token_ids unused.
//  - cosine(cen,m) scale-invariant => accumulate unnormalized m~ = sum_c e^a v.
//  - R10: timed window = ~184us fixed ws-poison fills (2x ~92us), untouchable.
//  - R12/R13: 1024 blocks = +30us (DRAM stream effect) => KEEP 512 blocks.
//  - R14 (233.8, best): double-buffer LDS, 1 barrier/group, 1-deep prefetch.
//    k_vam ~45us = 3.5 TB/s: loads issued at iter top are consumed at END of
//    the SAME iteration -> in-flight window (~400cy) < HBM latency (~900cy).
//  - R15/R16 (this version; R15 never ran - broker timeout): depth-2
//    prefetch. Sets A/B; L(g)->set[g&1]; iter g issues L(g+2) into the set
//    phase1(g) freed. Each load rides a full iteration before use; waves
//    keep 16 loads outstanding continuously. +64 VGPR, under (256,2) cap;
//    occupancy unchanged (2 blocks/CU from grid).

typedef float nfloat4 __attribute__((ext_vector_type(4)));

__device__ __forceinline__ void n4add(nfloat4& a, const nfloat4& b) { a += b; }

#define ISSUE(Xs, Ys, cidx)                                                   \
    do {                                                                      \
        const nfloat4* ctx4_ =                                                \
            (const nfloat4*)ctx + (size_t)(b * NC + (cidx)) * NS * ND4;       \
        _Pragma("unroll")                                                     \
        for (int s = 0; s < NS; ++s)                                          \
            Xs[s] = __builtin_nontemporal_load(&ctx4_[s * ND4 + i0]);         \
        if (has1) {                                                           \
            _Pragma("unroll")                                                 \
            for (int s = 0; s < NS; ++s)                                      \
                Ys[s] = __builtin_nontemporal_load(&ctx4_[s * ND4 + i1]);     \
        }                                                                     \
    } while (0)

// consumes Xs/Ys (destructive tree mean); writes v,ea tiles for buffer BUF
#define PHASE1(Xs, Ys, BUF)                                                   \
    do {                                                                      \
        n4add(Xs[0], Xs[1]); n4add(Xs[2], Xs[3]);                             \
        n4add(Xs[4], Xs[5]); n4add(Xs[6], Xs[7]);                             \
        n4add(Xs[0], Xs[2]); n4add(Xs[4], Xs[6]);                             \
        n4add(Xs[0], Xs[4]);                                                  \
        n4add(Ys[0], Ys[1]); n4add(Ys[2], Ys[3]);                             \
        n4add(Ys[4], Ys[5]); n4add(Ys[6], Ys[7]);                             \
        n4add(Ys[0], Ys[2]); n4add(Ys[4], Ys[6]);                             \
        n4add(Ys[0], Ys[4]);                                                  \
        nfloat4 s0 = Xs[0] * 0.125f;                                          \
        nfloat4 s1 = Ys[0] * 0.125f;      /* zero beyond lane 10 */           \
        ((nfloat4*)vl[BUF][w])[i0] = s0;                                      \
        if (has1) ((nfloat4*)vl[BUF][w])[i1] = s1;                            \
        float pk[NK];                                                         \
        _Pragma("unroll")                                                     \
        for (int k = 0; k < NK; ++k) {                                        \
            nfloat4 ca = cen4[k * ND4 + i0];                                  \
            float p = ca.x*s0.x + ca.y*s0.y + ca.z*s0.z + ca.w*s0.w;          \
            if (has1) {                                                       \
                nfloat4 cb = cen4[k * ND4 + i1];                              \
                p += cb.x*s1.x + cb.y*s1.y + cb.z*s1.z + cb.w*s1.w;           \
            }                                                                 \
            pk[k] = p;                                                        \
        }                                                                     \
        const bool bb0 = (lane & 1) != 0;                                     \
        float rr[4];                                                          \
        _Pragma("unroll")                                                     \
        for (int j = 0; j < 4; ++j) {                                         \
            float keep = bb0 ? pk[2*j+1] : pk[2*j];                           \
            float send = bb0 ? pk[2*j]   : pk[2*j+1];                         \
            rr[j] = keep + __shfl_xor(send, 1);                               \
        }                                                                     \
        const bool bb1 = (lane & 2) != 0;                                     \
        float qq0, qq1;                                                       \
        { float keep = bb1 ? rr[1] : rr[0]; float send = bb1 ? rr[0] : rr[1]; \
          qq0 = keep + __shfl_xor(send, 2); }                                 \
        { float keep = bb1 ? rr[3] : rr[2]; float send = bb1 ? rr[2] : rr[3]; \
          qq1 = keep + __shfl_xor(send, 2); }                                 \
        const bool bb2 = (lane & 4) != 0;                                     \
        float uu;                                                             \
        { float keep = bb2 ? qq1 : qq0; float send = bb2 ? qq0 : qq1;         \
          uu = keep + __shfl_xor(send, 4); }                                  \
        uu += __shfl_xor(uu, 8);                                              \
        uu += __shfl_xor(uu, 16);                                             \
        uu += __shfl_xor(uu, 32);                                             \
        if (lane < NK) al[BUF][w][lane] = __expf(uu * 0.057735026919f);       \
    } while (0)

#define PHASE2(BUF, CN)                                                       \
    do {                                                                      \
        for (int cc = 0; cc < (CN); ++cc) {                                   \
            nfloat4 a0 = ((const nfloat4*)al[BUF][cc])[0];                    \
            nfloat4 a1 = ((const nfloat4*)al[BUF][cc])[1];                    \
            float vv0 = vl[BUF][cc][t];                                       \
            acc0[0] += a0.x * vv0; acc0[1] += a0.y * vv0;                     \
            acc0[2] += a0.z * vv0; acc0[3] += a0.w * vv0;                     \
            acc0[4] += a1.x * vv0; acc0[5] += a1.y * vv0;                     \
            acc0[6] += a1.z * vv0; acc0[7] += a1.w * vv0;                     \
            if (hasd1) {                                                      \
                float vv1 = vl[BUF][cc][256 + t];                             \
                acc1[0] += a0.x * vv1; acc1[1] += a0.y * vv1;                 \
                acc1[2] += a0.z * vv1; acc1[3] += a0.w * vv1;                 \
                acc1[4] += a1.x * vv1; acc1[5] += a1.y * vv1;                 \
                acc1[6] += a1.z * vv1; acc1[7] += a1.w * vv1;                 \
            }                                                                 \
        }                                                                     \
    } while (0)

// ---------------------------------------------------------------------------
// K1: block = (b, cg) owns 32 consecutive c's as 8 groups of 4 (wave w ->
// c = base + g*4 + w). Depth-2 software pipeline: L(g)->set[g&1]; per iter:
// barrier; issue L(g+2); phase2(g) from buf[g&1]; phase1(g+1)->buf[(g+1)&1].
// ---------------------------------------------------------------------------
__global__ __launch_bounds__(256, 2) void k_vam(const float* __restrict__ ctx,
                                                const float* __restrict__ cen,
                                                float* __restrict__ part) {
    const int b    = blockIdx.x >> 4;        // 16 cgroups per b
    const int cg   = blockIdx.x & 15;
    const int w    = threadIdx.x >> 6;       // 4 waves
    const int lane = threadIdx.x & 63;
    const int t    = threadIdx.x;
    const int i0 = lane;
    const int i1 = lane + 64;
    const bool has1  = (i1 < ND4);           // lanes 0..10 own a second float4
    const bool hasd1 = (t < ND - 256);       // threads 0..43 own d = 256+t

    __shared__ float vl[2][4][ND4 * 4 + 4];  // v tiles, padded rows
    __shared__ float al[2][4][NK];           // ea tiles

    const nfloat4* cen4 = (const nfloat4*)cen + (size_t)b * NK * ND4;

    float acc0[NK] = {};                     // m~ partial at d = t
    float acc1[NK] = {};                     // m~ partial at d = 256+t (t<44)

    const int cbase0 = cg * (GPB * 4);

    nfloat4 XA[NS], XB[NS];
    nfloat4 YA[NS] = {}, YB[NS] = {};        // lanes >= 11 stay zero forever

    // ---- prologue: L(0)->A, L(1)->B (both always in-range: max c = 487),
    //      then phase1(0) from A (compiler waits A with B's 16 in flight) ----
    ISSUE(XA, YA, cbase0 + w);
    ISSUE(XB, YB, cbase0 + 4 + w);
    PHASE1(XA, YA, 0);

    for (int gp = 0; gp < GPB; gp += 2) {
        // ================= g = gp (even): phase2 buf0 =================
        __syncthreads();                     // buf0 ready; buf1 free
        if (gp + 2 < GPB) {
            const int cpre = cbase0 + (gp + 2) * 4 + w;
            if (cpre < NC) ISSUE(XA, YA, cpre);   // wave-uniform guard
        }
        PHASE2(0, min(4, NC - (cbase0 + gp * 4)));
        {
            const int cnx = cbase0 + (gp + 1) * 4 + w;
            if (cnx < NC) PHASE1(XB, YB, 1);      // gp+1 <= 7 always
        }
        asm volatile("" ::: "memory");

        // ================= g = gp+1 (odd): phase2 buf1 =================
        __syncthreads();                     // buf1 ready; buf0 free
        if (gp + 3 < GPB) {
            const int cpre = cbase0 + (gp + 3) * 4 + w;
            if (cpre < NC) ISSUE(XB, YB, cpre);
        }
        PHASE2(1, min(4, NC - (cbase0 + (gp + 1) * 4)));
        if (gp + 2 < GPB) {
            const int cnx = cbase0 + (gp + 2) * 4 + w;
            if (cnx < NC) PHASE1(XA, YA, 0);
        }
        asm volatile("" ::: "memory");
    }

    // ---- one coalesced part write per k ----
#pragma unroll
    for (int k = 0; k < NK; ++k) {
        float* pp = part + (((size_t)(b * NK + k)) * NCG + cg) * ND;
        pp[t] = acc0[k];
        if (hasd1) pp[256 + t] = acc1[k];
    }
}

// ---------------------------------------------------------------------------
// K2: per b — wave w owns k=w: sum the 16 m~ chunk-partials along d (contiguous
// [NCG][ND] panel per (b,k)), cosine vs cen row, then softmax/argmax/pooled.
// ---------------------------------------------------------------------------
__global__ __launch_bounds__(512) void k_fin2(const float* __restrict__ part,
                                              const float* __restrict__ cen,
                                              float* __restrict__ out) {
    const int b    = blockIdx.x;
    const int w    = threadIdx.x >> 6;       // = k
    const int lane = threadIdx.x & 63;
    __shared__ float sred[NK];
    __shared__ int bidx;

    const float* pp = part + ((size_t)b * NK + w) * NCG * ND;
    const float* cp = cen + (size_t)(b * NK + w) * ND;
    float num = 0.f, n1 = 0.f, n2 = 0.f;
    for (int d = lane; d < ND; d += 64) {
        float mval = 0.f;
#pragma unroll
        for (int cg = 0; cg < NCG; ++cg) mval += pp[cg * ND + d];
        float cv = cp[d];
        num += cv * mval; n1 += cv * cv; n2 += mval * mval;
    }
#pragma unroll
    for (int off = 32; off; off >>= 1) {
        num += __shfl_down(num, off);
        n1  += __shfl_down(n1, off);
        n2  += __shfl_down(n2, off);
    }
    if (lane == 0) {
        float denom = fmaxf(sqrtf(n1), EPS_COS) * fmaxf(sqrtf(n2), EPS_COS);
        sred[w] = num / denom;
    }
    __syncthreads();

    if (threadIdx.x == 0) {
        float mx = sred[0];
#pragma unroll
        for (int k = 1; k < NK; ++k) mx = fmaxf(mx, sred[k]);
        float e[NK], sum = 0.f;
#pragma unroll
        for (int k = 0; k < NK; ++k) { e[k] = __expf(sred[k] - mx); sum += e[k]; }
        float invs = 1.f / sum;
        int best = 0; float bv = sred[0];
#pragma unroll
        for (int k = 1; k < NK; ++k) if (sred[k] > bv) { bv = sred[k]; best = k; }
#pragma unroll
        for (int k = 0; k < NK; ++k)
            out[(size_t)NB * ND + b * NK + k] = e[k] * invs;
        bidx = best;
    }
    __syncthreads();

    const float* src = cen + (size_t)(b * NK + bidx) * ND;
    for (int idx = threadIdx.x; idx < ND; idx += 512)
        out[(size_t)b * ND + idx] = src[idx];
}

extern "C" void kernel_launch(void* const* d_in, const int* in_sizes, int n_in,
                              void* d_out, int out_size, void* d_ws, size_t ws_size,
                              hipStream_t stream) {
    // d_in[0]=center_pos, d_in[1]=query_token_ids: unused (log-weight constant)
    const float* cen = (const float*)d_in[2];   // [B,K,d]
    const float* ctx = (const float*)d_in[3];   // [B,C,S,d]
    float* out = (float*)d_out;                 // pooled [B,d] then q [B,K]

    float* part = (float*)d_ws;                 // [B][K][NCG][ND] = 4.9 MB

    k_vam<<<dim3(NB * NCG), dim3(256), 0, stream>>>(ctx, cen, part);
    k_fin2<<<dim3(NB), dim3(512), 0, stream>>>(part, cen, out);
}